// Round 10
// baseline (168.292 us; speedup 1.0000x reference)
//
#include <hip/hip_runtime.h>

#define N_NODES 50000
#define F_IN 128
#define OUT_F 128
#define JF 256
#define EDGES 600000
#define BN_EPS 1e-5f
#define MAXDEG 48
#define NPART 8
#define PART_ROWS 6250   // N_NODES / NPART
#define CHUNK_E 2048
#define NCHUNK 586       // 586*2048 = 1200128 >= 2E

#define SCAT_B (NPART * NCHUNK)   // 4688
#define CONVX_B 6250     // N*F_IN/4/256
#define CONVW_B 32       // 128*256/4/256
#define BUILD_B (SCAT_B + CONVX_B + CONVW_B)
#define ROWS_PB 32
#define FUSE_B 1563      // ceil(N/32)
#define NCOPY 16         // stats replication

typedef __attribute__((ext_vector_type(8))) short short8;
typedef __attribute__((ext_vector_type(4))) float floatx4;
typedef __attribute__((ext_vector_type(4))) unsigned short ushortx4;

static __device__ __forceinline__ unsigned short f2bf(float f) {
    unsigned int x = __float_as_uint(f);
    unsigned int r = (x + 0x7fffu + ((x >> 16) & 1u)) >> 16;
    return (unsigned short)r;
}
static __device__ __forceinline__ float bflo(unsigned int p) { return __uint_as_float(p << 16); }
static __device__ __forceinline__ float bfhi(unsigned int p) { return __uint_as_float(p & 0xffff0000u); }

// ---------------------------------------------------------------------------
// Fused build: XCD-partitioned row-major ELL scatter + x/W -> bf16 converts.
// ---------------------------------------------------------------------------
__global__ __launch_bounds__(256) void build_kernel(
    const int* __restrict__ rows0, const int* __restrict__ cols0, const float* __restrict__ vals0,
    const int* __restrict__ rows1, const int* __restrict__ cols1, const float* __restrict__ vals1,
    int* __restrict__ cnt0, int* __restrict__ cnt1,
    unsigned int* __restrict__ pe0, unsigned int* __restrict__ pe1,
    const floatx4* __restrict__ x4, ushortx4* __restrict__ xb4,
    const floatx4* __restrict__ W4, ushortx4* __restrict__ Wb4)
{
    int bid = blockIdx.x;
    int tid = threadIdx.x;
    if (bid < SCAT_B) {
        unsigned part = (unsigned)(bid & (NPART - 1));
        int c0 = (bid >> 3) * CHUNK_E;

        bool pure0 = (c0 + CHUNK_E <= EDGES);
        bool pure1 = (c0 >= EDGES) && (c0 + CHUNK_E <= 2 * EDGES);
        if (pure0 || pure1) {
            const int*   rows = pure1 ? rows1 : rows0;
            const int*   cols = pure1 ? cols1 : cols0;
            const float* vals = pure1 ? vals1 : vals0;
            int*          cnt = pure1 ? cnt1 : cnt0;
            unsigned int*  pe = pure1 ? pe1 : pe0;
            int eb = pure1 ? c0 - EDGES : c0;
            #pragma unroll
            for (int g = 0; g < 2; ++g) {
                int e = eb + g * 1024 + tid * 4;
                int4 rv = *(const int4*)(rows + e);
                int rr[4] = {rv.x, rv.y, rv.z, rv.w};
                #pragma unroll
                for (int j = 0; j < 4; ++j) {
                    int r = rr[j];
                    if ((unsigned)r / (unsigned)PART_ROWS == part) {
                        int ee = e + j;
                        int c = cols[ee];
                        float v = vals[ee];
                        int p = atomicAdd(&cnt[r], 1);
                        if (p < MAXDEG)
                            pe[(size_t)r * MAXDEG + p] = ((unsigned int)c << 16) | f2bf(v);
                    }
                }
            }
        } else {
            for (int i = 0; i < CHUNK_E / 256; ++i) {
                int e = c0 + i * 256 + tid;
                if (e < 2 * EDGES) {
                    bool s1 = e >= EDGES;
                    int ee = s1 ? e - EDGES : e;
                    int r = s1 ? rows1[ee] : rows0[ee];
                    if ((unsigned)r / (unsigned)PART_ROWS == part) {
                        int c = s1 ? cols1[ee] : cols0[ee];
                        float v = s1 ? vals1[ee] : vals0[ee];
                        int* cnt = s1 ? cnt1 : cnt0;
                        unsigned int* pe = s1 ? pe1 : pe0;
                        int p = atomicAdd(&cnt[r], 1);
                        if (p < MAXDEG)
                            pe[(size_t)r * MAXDEG + p] = ((unsigned int)c << 16) | f2bf(v);
                    }
                }
            }
        }
    } else if (bid < SCAT_B + CONVX_B) {
        int i = (bid - SCAT_B) * 256 + tid;
        floatx4 v = __builtin_nontemporal_load(&x4[i]);
        ushortx4 o;
        o.x = f2bf(v.x); o.y = f2bf(v.y); o.z = f2bf(v.z); o.w = f2bf(v.w);
        __builtin_nontemporal_store(o, &xb4[i]);
    } else {
        int i = (bid - SCAT_B - CONVX_B) * 256 + tid;
        floatx4 v = W4[i];
        ushortx4 o;
        o.x = f2bf(v.x); o.y = f2bf(v.y); o.z = f2bf(v.z); o.w = f2bf(v.w);
        Wb4[i] = o;
    }
}

// ---------------------------------------------------------------------------
// ELL record accumulate; _m variant masks (boundary slots), _u unconditional.
// ---------------------------------------------------------------------------
static __device__ __forceinline__ void rec_u(
    unsigned int q, int lane,
    const unsigned int* __restrict__ xb32, float& A0, float& A1)
{
    unsigned int xv = xb32[(q >> 16) * 64 + lane];
    float vv = __uint_as_float(q << 16);
    A0 += vv * bflo(xv);
    A1 += vv * bfhi(xv);
}
static __device__ __forceinline__ void rec_m(
    unsigned int q, bool on, int lane,
    const unsigned int* __restrict__ xb32, float& A0, float& A1)
{
    unsigned int idx = on ? (q >> 16) : 0u;
    float vv = on ? __uint_as_float(q << 16) : 0.0f;
    unsigned int xv = xb32[idx * 64 + lane];
    A0 += vv * bflo(xv);
    A1 += vv * bfhi(xv);
}

// ---------------------------------------------------------------------------
// Fused gather + MFMA GEMM + BN stats. 32 rows/block, 4 waves, 8 rows/wave.
// Phase 0: cooperative staging of ELL records (first 24/side) + cnts to LDS.
// Phase 1: per row: scalar degree, wave-uniform group skips (s_cbranch),
//          branchless within group; gathers of a live group issue together.
// Phase 2: 32x128 tile; wave w: 2 row-tiles x 2 col-tiles, mfma 16x16x32.
// ---------------------------------------------------------------------------
__global__ __launch_bounds__(256, 6) void gather_gemm(
    const unsigned int* __restrict__ xb32,
    const int* __restrict__ cnt0, const unsigned int* __restrict__ pe0,
    const int* __restrict__ cnt1, const unsigned int* __restrict__ pe1,
    const ushort* __restrict__ Wb, const float* __restrict__ bias,
    float* __restrict__ y, float* __restrict__ stats)
{
    __shared__ unsigned int hsu[ROWS_PB * 128];  // 16 KB swizzled h rows
    __shared__ uint4 recs[2][ROWS_PB][6];        // 6 KB staged ELL records
    __shared__ int   lcnt[2][ROWS_PB];           // 256 B
    __shared__ float lstat[256];                 // 1 KB

    int tid = threadIdx.x;
    int lane = tid & 63;
    int w = tid >> 6;
    int wu = __builtin_amdgcn_readfirstlane(w);
    int row0 = blockIdx.x * ROWS_PB;

    lstat[tid] = 0.f;

    // ---- phase 0: stage records + counts into LDS ----
    {
        // 2*32*6 = 384 uint4 records; thread tid covers idx=tid and idx=256+tid
        int idx = tid;
        #pragma unroll
        for (int pass = 0; pass < 2; ++pass) {
            if (idx < 384) {
                int lr = idx / 12;
                int rem = idx - lr * 12;
                int side = rem >= 6;
                int g = rem - side * 6;
                int r = row0 + lr; if (r >= N_NODES) r = N_NODES - 1;
                const unsigned int* pe = side ? pe1 : pe0;
                recs[side][lr][g] = *(const uint4*)(pe + (size_t)r * MAXDEG + g * 4);
            }
            idx += 256;
        }
        if (tid < 64) {
            int side = tid >= ROWS_PB;
            int lr = tid & (ROWS_PB - 1);
            int r = row0 + lr;
            int d = 0;
            if (r < N_NODES) d = (side ? cnt1 : cnt0)[r];
            if (d > MAXDEG) d = MAXDEG;
            lcnt[side][lr] = d;
        }
    }
    __syncthreads();

    // ---- phase 1: gather 8 rows per wave ----
    for (int rr = 0; rr < 8; ++rr) {
        int lr = wu * 8 + rr;
        int r = row0 + lr;
        int d0 = __builtin_amdgcn_readfirstlane(lcnt[0][lr]);
        int d1 = __builtin_amdgcn_readfirstlane(lcnt[1][lr]);

        float aL0 = 0.f, aL1 = 0.f, aR0 = 0.f, aR1 = 0.f;

        #pragma unroll
        for (int g = 0; g < 6; ++g) {
            if (g * 4 < d0) {
                uint4 q = recs[0][lr][g];
                rec_u(q.x, lane, xb32, aL0, aL1);
                rec_m(q.y, g * 4 + 1 < d0, lane, xb32, aL0, aL1);
                rec_m(q.z, g * 4 + 2 < d0, lane, xb32, aL0, aL1);
                rec_m(q.w, g * 4 + 3 < d0, lane, xb32, aL0, aL1);
            }
        }
        #pragma unroll
        for (int g = 0; g < 6; ++g) {
            if (g * 4 < d1) {
                uint4 q = recs[1][lr][g];
                rec_u(q.x, lane, xb32, aR0, aR1);
                rec_m(q.y, g * 4 + 1 < d1, lane, xb32, aR0, aR1);
                rec_m(q.z, g * 4 + 2 < d1, lane, xb32, aR0, aR1);
                rec_m(q.w, g * 4 + 3 < d1, lane, xb32, aR0, aR1);
            }
        }
        // rare tails (deg > 24): straight from global
        if (d0 > 24)
            for (int p = 24; p < d0; ++p)
                rec_u(pe0[(size_t)r * MAXDEG + p], lane, xb32, aL0, aL1);
        if (d1 > 24)
            for (int p = 24; p < d1; ++p)
                rec_u(pe1[(size_t)r * MAXDEG + p], lane, xb32, aR0, aR1);

        unsigned int sw = (unsigned int)((lr & 7) << 4);
        unsigned int offL = ((unsigned int)(lr * 512 + lane * 4)) ^ sw;
        unsigned int offR = ((unsigned int)(lr * 512 + 256 + lane * 4)) ^ sw;
        *(unsigned int*)((char*)hsu + offL) =
            (unsigned int)f2bf(aL0) | ((unsigned int)f2bf(aL1) << 16);
        *(unsigned int*)((char*)hsu + offR) =
            (unsigned int)f2bf(aR0) | ((unsigned int)f2bf(aR1) << 16);
    }
    __syncthreads();

    // ---- phase 2: 32x32 per wave (2 row-tiles x 2 col-tiles), K=256 ----
    floatx4 acc[2][2];
    #pragma unroll
    for (int rt = 0; rt < 2; ++rt)
        #pragma unroll
        for (int c = 0; c < 2; ++c)
            acc[rt][c] = (floatx4){0.f, 0.f, 0.f, 0.f};

    int colb = lane & 15;
    int kg = lane >> 4;
    const char* hbase = (const char*)hsu;
    const ushort* wp = Wb + (size_t)(w * 32 + colb) * JF + kg * 8;

    #pragma unroll
    for (int k0 = 0; k0 < 8; ++k0) {
        #pragma unroll
        for (int rt = 0; rt < 2; ++rt) {
            int arow = rt * 16 + colb;
            unsigned int asw = (unsigned int)((arow & 7) << 4);
            unsigned int aoff = ((unsigned int)(arow * 512 + k0 * 64 + kg * 16)) ^ asw;
            short8 a = *(const short8*)(hbase + aoff);
            #pragma unroll
            for (int c = 0; c < 2; ++c) {
                short8 b = *(const short8*)(wp + c * 16 * JF + k0 * 32);
                acc[rt][c] = __builtin_amdgcn_mfma_f32_16x16x32_bf16(a, b, acc[rt][c], 0, 0, 0);
            }
        }
    }

    // ---- epilogue: bias, y write (guarded), stats ----
    int rq = kg * 4;
    #pragma unroll
    for (int rt = 0; rt < 2; ++rt) {
        #pragma unroll
        for (int c = 0; c < 2; ++c) {
            int col = w * 32 + c * 16 + colb;
            float bv = bias[col];
            float s = 0.f, s2 = 0.f;
            #pragma unroll
            for (int q = 0; q < 4; ++q) {
                int row = row0 + rt * 16 + rq + q;
                if (row < N_NODES) {
                    float val = acc[rt][c][q] + bv;
                    y[(size_t)row * OUT_F + col] = val;
                    s += val; s2 += val * val;
                }
            }
            atomicAdd(&lstat[col], s);
            atomicAdd(&lstat[128 + col], s2);
        }
    }
    __syncthreads();
    float* sdst = stats + (size_t)(blockIdx.x & (NCOPY - 1)) * 256;
    atomicAdd(&sdst[tid], lstat[tid]);
}

// ---------------------------------------------------------------------------
// BN scale/shift prep: fold NCOPY stat replicas.
// ---------------------------------------------------------------------------
__global__ void bn_prep(const float* __restrict__ stats,
                        const float* __restrict__ gamma,
                        const float* __restrict__ beta,
                        float* __restrict__ ss)
{
    int o = threadIdx.x;
    if (o >= OUT_F) return;
    float s = 0.f, s2 = 0.f;
    #pragma unroll
    for (int c = 0; c < NCOPY; ++c) {
        s  += stats[c * 256 + o];
        s2 += stats[c * 256 + 128 + o];
    }
    float inv_n = 1.0f / (float)N_NODES;
    float mean = s * inv_n;
    float var  = s2 * inv_n - mean * mean;
    float sc = rsqrtf(var + BN_EPS) * gamma[o];
    ss[o] = sc;
    ss[OUT_F + o] = beta[o] - mean * sc;
}

// ---------------------------------------------------------------------------
// BN apply.
// ---------------------------------------------------------------------------
__global__ __launch_bounds__(256) void bn_apply(
    float* __restrict__ y, const float* __restrict__ ss)
{
    size_t i = (size_t)blockIdx.x * blockDim.x + threadIdx.x;
    size_t total = (size_t)N_NODES * OUT_F / 4;
    if (i >= total) return;

    int c4 = (int)(i & (OUT_F / 4 - 1));
    float4 v  = ((const float4*)y)[i];
    float4 sc = ((const float4*)ss)[c4];
    float4 sh = ((const float4*)(ss + OUT_F))[c4];
    v.x = v.x * sc.x + sh.x;
    v.y = v.y * sc.y + sh.y;
    v.z = v.z * sc.z + sh.z;
    v.w = v.w * sc.w + sh.w;
    ((float4*)y)[i] = v;
}

extern "C" void kernel_launch(void* const* d_in, const int* in_sizes, int n_in,
                              void* d_out, int out_size, void* d_ws, size_t ws_size,
                              hipStream_t stream)
{
    const float* x     = (const float*)d_in[0];
    const int*   rows0 = (const int*)  d_in[1];
    const int*   cols0 = (const int*)  d_in[2];
    const float* vals0 = (const float*)d_in[3];
    const int*   rows1 = (const int*)  d_in[4];
    const int*   cols1 = (const int*)  d_in[5];
    const float* vals1 = (const float*)d_in[6];
    const float* W     = (const float*)d_in[7];
    const float* b     = (const float*)d_in[8];
    const float* gamma = (const float*)d_in[9];
    const float* beta  = (const float*)d_in[10];

    float* y = (float*)d_out;

    // workspace layout
    ushort* xb = (ushort*)d_ws;                                  // N*128 bf16 (12.8 MB)
    ushort* Wb = xb + (size_t)N_NODES * F_IN;                    // 128*256 bf16 (64 KB)
    unsigned int* pe0 = (unsigned int*)(Wb + OUT_F * JF);        // N*MAXDEG (9.6 MB), row-major
    unsigned int* pe1 = pe0 + (size_t)N_NODES * MAXDEG;          // N*MAXDEG (9.6 MB)
    int* cnt0 = (int*)(pe1 + (size_t)N_NODES * MAXDEG);          // N   <- zero region
    int* cnt1 = cnt0 + N_NODES;                                  // N
    float* stats = (float*)(cnt1 + N_NODES);                     // NCOPY*256
    float* ss    = stats + NCOPY * 256;                          // 256

    // zero cnt0, cnt1, stats
    hipMemsetAsync(cnt0, 0, (2 * (size_t)N_NODES + NCOPY * 256) * sizeof(int), stream);

    // partitioned ELL build + bf16 conversions
    build_kernel<<<BUILD_B, 256, 0, stream>>>(
        rows0, cols0, vals0, rows1, cols1, vals1,
        cnt0, cnt1, pe0, pe1,
        (const floatx4*)x, (ushortx4*)xb, (const floatx4*)W, (ushortx4*)Wb);

    // fused gather + GEMM + stats
    gather_gemm<<<FUSE_B, 256, 0, stream>>>(
        (const unsigned int*)xb, cnt0, pe0, cnt1, pe1, Wb, b, y, stats);

    // BN
    bn_prep<<<1, 128, 0, stream>>>(stats, gamma, beta, ss);
    bn_apply<<<CONVX_B, 256, 0, stream>>>(y, ss);
}